// Round 1
// baseline (131.563 us; speedup 1.0000x reference)
//
#include <hip/hip_runtime.h>

#define NTOT (8 * 512 * 512)   // 2097152 scores
#define N4   (NTOT / 4)
#define KSEL 2048
#define HW   (512 * 512)
#define NEGF (-1e9f)

struct WS {
  unsigned hist[256];
  unsigned prefix, rank, vstar, cntM;
  unsigned depmask[64];
  unsigned pad[2];                  // keep keys 8B-aligned (1024+16+256+8 = 1304 -> pad to 1312? ensure below)
  unsigned long long keys[4096];    // compacted (ov<<32)|~idx
  float    cval[KSEL];
  int      cx[KSEL], cy[KSEL], cb[KSEL];
  unsigned valid[KSEL], cnt[KSEL];
  unsigned short list[KSEL * 8];
  unsigned keep[KSEL];
};

__device__ __forceinline__ unsigned ordf(float x) {
  unsigned u = __float_as_uint(x);
  return (u & 0x80000000u) ? ~u : (u | 0x80000000u);
}
__device__ __forceinline__ float unordf(unsigned ov) {
  return __uint_as_float((ov & 0x80000000u) ? (ov & 0x7fffffffu) : ~ov);
}

__global__ void k_zero(WS* ws) {
  int t = threadIdx.x;
  ws->hist[t] = 0;
  if (t < 64) ws->depmask[t] = 0;
  if (t == 0) { ws->prefix = 0; ws->rank = KSEL; ws->vstar = 0; ws->cntM = 0; }
}

// one 8-bit radix-select histogram pass over the masked scores
__global__ void k_hist(const float* __restrict__ probs, WS* ws, int shift, unsigned mask) {
  __shared__ unsigned h[256];
  int t = threadIdx.x;
  h[t] = 0;
  __syncthreads();
  unsigned pre = ws->prefix;
  int stride = gridDim.x * blockDim.x;
  for (int i = blockIdx.x * blockDim.x + t; i < N4; i += stride) {
    float4 v = reinterpret_cast<const float4*>(probs)[i];
    float a0 = v.x, a1 = v.y, a2 = v.z, a3 = v.w;
    float m0 = (a0 >= 0.6f) ? a0 : NEGF;
    float m1 = (a1 >= 0.6f) ? a1 : NEGF;
    float m2 = (a2 >= 0.6f) ? a2 : NEGF;
    float m3 = (a3 >= 0.6f) ? a3 : NEGF;
    unsigned o0 = ordf(m0), o1 = ordf(m1), o2 = ordf(m2), o3 = ordf(m3);
    if ((o0 & mask) == pre) atomicAdd(&h[(o0 >> shift) & 255u], 1u);
    if ((o1 & mask) == pre) atomicAdd(&h[(o1 >> shift) & 255u], 1u);
    if ((o2 & mask) == pre) atomicAdd(&h[(o2 >> shift) & 255u], 1u);
    if ((o3 & mask) == pre) atomicAdd(&h[(o3 >> shift) & 255u], 1u);
  }
  __syncthreads();
  if (h[t]) atomicAdd(&ws->hist[t], h[t]);
}

// pick the digit bin containing the remaining rank; update prefix/rank; zero hist
__global__ void k_resolve(WS* ws, int shift, int last) {
  __shared__ unsigned c[256];
  int t = threadIdx.x;
  c[t] = ws->hist[t];
  __syncthreads();
  // inclusive suffix sum: c[b] = sum_{d>=b} hist[d]
  for (int off = 1; off < 256; off <<= 1) {
    unsigned add = (t + off < 256) ? c[t + off] : 0u;
    __syncthreads();
    c[t] += add;
    __syncthreads();
  }
  unsigned r = ws->rank;
  unsigned cum = c[t];
  unsigned cumN = (t < 255) ? c[t + 1] : 0u;
  if (cum >= r && cumN < r) {   // unique bin
    unsigned np = ws->prefix | ((unsigned)t << shift);
    ws->prefix = np;
    ws->rank = r - cumN;
    if (last) ws->vstar = np;
  }
  ws->hist[t] = 0;
}

__global__ void k_compact(const float* __restrict__ probs, WS* ws) {
  unsigned vs = ws->vstar;
  int t = blockIdx.x * blockDim.x + threadIdx.x;
  int stride = gridDim.x * blockDim.x;
  for (int i = t; i < N4; i += stride) {
    float4 v = reinterpret_cast<const float4*>(probs)[i];
    float a[4] = {v.x, v.y, v.z, v.w};
    #pragma unroll
    for (int s = 0; s < 4; s++) {
      float val = (a[s] >= 0.6f) ? a[s] : NEGF;
      unsigned ov = ordf(val);
      if (ov >= vs) {
        unsigned pos = atomicAdd(&ws->cntM, 1u);
        if (pos < 4096u) {
          unsigned idx = (unsigned)(i * 4 + s);
          ws->keys[pos] = ((unsigned long long)ov << 32) | (~idx);
        }
      }
    }
  }
}

// exact rank of each compacted key (value desc, index asc) -> scatter into rank order
__global__ void __launch_bounds__(256) k_rank(WS* ws) {
  __shared__ unsigned long long sk[4096];
  unsigned Mc = min(ws->cntM, 4096u);
  for (int j = threadIdx.x; j < 4096; j += 256) sk[j] = (j < (int)Mc) ? ws->keys[j] : 0ULL;
  __syncthreads();
  int i = blockIdx.x * 256 + threadIdx.x;
  if (i >= (int)Mc) {
    // robustness: if fewer than K candidates exist, zero the unfilled slots
    if (i < KSEL) {
      ws->cval[i] = NEGF; ws->valid[i] = 0u;
      ws->cx[i] = 0; ws->cy[i] = 0; ws->cb[i] = 0;
    }
    return;
  }
  unsigned long long ki = sk[i];
  int rk = 0;
  for (int j = 0; j < (int)Mc; j++) rk += (sk[j] > ki) ? 1 : 0;
  if (rk < KSEL) {
    unsigned ov = (unsigned)(ki >> 32);
    unsigned idx = ~((unsigned)(ki & 0xffffffffu));
    float val = unordf(ov);
    int b = (int)(idx >> 18);
    int rem = (int)(idx & 0x3ffffu);
    int y = rem >> 9, x = rem & 511;
    ws->cval[rk] = val;
    ws->cx[rk] = x; ws->cy[rk] = y; ws->cb[rk] = b;
    ws->valid[rk] = (val >= 0.6f) ? 1u : 0u;
  }
}

// suppression graph: earlier-ranked 8-neighbors in same image (== IoU>0.5 for this geometry)
__global__ void k_adj(WS* ws) {   // grid 2048 x 64 threads (1 wave/candidate)
  int i = blockIdx.x;
  __shared__ unsigned lcnt;
  if (threadIdx.x == 0) lcnt = 0;
  __syncthreads();
  int xi = ws->cx[i], yi = ws->cy[i], bi = ws->cb[i];
  for (int s = 0; s < 32; s++) {
    int j = s * 64 + threadIdx.x;
    if (j < i) {
      int dx = ws->cx[j] - xi, dy = ws->cy[j] - yi;
      if (ws->cb[j] == bi && dx >= -1 && dx <= 1 && dy >= -1 && dy <= 1) {
        unsigned p = atomicAdd(&lcnt, 1u);
        if (p < 8u) ws->list[i * 8 + p] = (unsigned short)j;
      }
    }
  }
  __syncthreads();
  if (threadIdx.x == 0) {
    ws->cnt[i] = min(lcnt, 8u);
    if (lcnt) atomicOr(&ws->depmask[i >> 5], 1u << (i & 31));
  }
}

// exact greedy NMS: independents keep=valid; dependents resolved serially in rank order
__global__ void __launch_bounds__(256) k_nms(WS* ws) {
  __shared__ unsigned char keepL[KSEL];
  __shared__ unsigned char cntL[KSEL];
  __shared__ unsigned short listL[KSEL * 8];
  __shared__ unsigned dm[64];
  int t = threadIdx.x;
  if (t < 64) dm[t] = ws->depmask[t];
  for (int i = t; i < KSEL; i += 256) {
    unsigned c = ws->cnt[i];
    cntL[i] = (unsigned char)c;
    keepL[i] = (unsigned char)(ws->valid[i] ? 1 : 0);
    for (unsigned l = 0; l < c; l++) listL[i * 8 + l] = ws->list[i * 8 + l];
  }
  __syncthreads();
  if (t == 0) {
    for (int w = 0; w < 64; w++) {
      unsigned m = dm[w];
      while (m) {
        int bit = __ffs(m) - 1;
        m &= m - 1;
        int i = w * 32 + bit;
        int c = cntL[i];
        int k = keepL[i];
        for (int l = 0; l < c; l++) k &= (keepL[listL[i * 8 + l]] ^ 1);
        keepL[i] = (unsigned char)k;
      }
    }
  }
  __syncthreads();
  for (int i = t; i < KSEL; i += 256) ws->keep[i] = keepL[i];
}

// bbreg + rerec epilogue; writes all K*5 outputs
__global__ void k_out(const float* __restrict__ reg, WS* ws, float* __restrict__ out) {
  int k = blockIdx.x * blockDim.x + threadIdx.x;
  if (k >= KSEL) return;
  float o0 = 0.f, o1 = 0.f, o2 = 0.f, o3 = 0.f, o4 = 0.f;
  if (ws->keep[k]) {
    int x = ws->cx[k], y = ws->cy[k], b = ws->cb[k];
    float val = ws->cval[k];
    long base = (long)b * 4 * HW + y * 512 + x;
    float r0 = reg[base + 0 * HW];
    float r1 = reg[base + 1 * HW];
    float r2 = reg[base + 2 * HW];
    float r3 = reg[base + 3 * HW];
    float x1 = (float)(4 * x + 2),  y1 = (float)(4 * y + 2);
    float x2 = (float)(4 * x + 24), y2 = (float)(4 * y + 24);
    float w = x2 - x1, h = y2 - y1;          // 22
    float q1 = x1 + r0 * w, q2 = y1 + r1 * h;
    float q3 = x2 + r2 * w, q4 = y2 + r3 * h;
    float ww = q3 - q1, hh = q4 - q2;
    float l = fmaxf(ww, hh);
    float X0 = q1 + ww * 0.5f - l * 0.5f;
    float Y0 = q2 + hh * 0.5f - l * 0.5f;
    o0 = X0; o1 = Y0; o2 = X0 + l; o3 = Y0 + l; o4 = val;
  }
  out[k * 5 + 0] = o0;
  out[k * 5 + 1] = o1;
  out[k * 5 + 2] = o2;
  out[k * 5 + 3] = o3;
  out[k * 5 + 4] = o4;
}

extern "C" void kernel_launch(void* const* d_in, const int* in_sizes, int n_in,
                              void* d_out, int out_size, void* d_ws, size_t ws_size,
                              hipStream_t stream) {
  (void)in_sizes; (void)n_in; (void)out_size; (void)ws_size;
  const float* reg   = (const float*)d_in[0];
  const float* probs = (const float*)d_in[1];
  float* out = (float*)d_out;
  WS* ws = (WS*)d_ws;

  k_zero<<<1, 256, 0, stream>>>(ws);
  k_hist<<<256, 256, 0, stream>>>(probs, ws, 24, 0x00000000u);
  k_resolve<<<1, 256, 0, stream>>>(ws, 24, 0);
  k_hist<<<256, 256, 0, stream>>>(probs, ws, 16, 0xff000000u);
  k_resolve<<<1, 256, 0, stream>>>(ws, 16, 0);
  k_hist<<<256, 256, 0, stream>>>(probs, ws, 8, 0xffff0000u);
  k_resolve<<<1, 256, 0, stream>>>(ws, 8, 0);
  k_hist<<<256, 256, 0, stream>>>(probs, ws, 0, 0xffffff00u);
  k_resolve<<<1, 256, 0, stream>>>(ws, 0, 1);
  k_compact<<<256, 256, 0, stream>>>(probs, ws);
  k_rank<<<16, 256, 0, stream>>>(ws);
  k_adj<<<2048, 64, 0, stream>>>(ws);
  k_nms<<<1, 256, 0, stream>>>(ws);
  k_out<<<8, 256, 0, stream>>>(reg, ws, out);
}